// Round 1
// baseline (3408.300 us; speedup 1.0000x reference)
//
#include <hip/hip_runtime.h>
#include <hip/hip_bf16.h>
#include <math.h>

#define D_MODEL 768
#define D_STATE 16
#define D_CONVW 4
#define D_INNER 1536
#define BATCH   2
#define SEQLEN  4096
#define NROWS   (BATCH*SEQLEN)       // 8192
#define NCHUNK  32
#define LCHUNK  (SEQLEN/NCHUNK)      // 128

// ---------------------------------------------------------------------------
// Generic fp32 GEMM: C[M,N] = A[M,K] @ B[K,N]  (+ optional softplus(acc+bias))
// A row-major w/ stride lda, B row-major stride ldb, C stride ldc.
// BM=BN=128, BK=16, 256 threads, 8x8 per thread.
// ---------------------------------------------------------------------------
template<int EPI>   // 0: none, 1: softplus(acc + bias[n])
__global__ __launch_bounds__(256) void gemm_f32(
    const float* __restrict__ A, int lda,
    const float* __restrict__ B, int ldb,
    float* __restrict__ C, int ldc,
    int M, int N, int K, const float* __restrict__ bias)
{
    const int BM = 128, BN = 128, BK = 16;
    __shared__ float As[BK][BM + 4];   // padded: breaks 8-way store conflict
    __shared__ float Bs[BK][BN + 4];

    const int bm = blockIdx.y * BM;
    const int bn = blockIdx.x * BN;
    const int tid = threadIdx.x;
    const int tx = tid % 16;           // output col group
    const int ty = tid / 16;           // output row group

    float acc[8][8];
    #pragma unroll
    for (int i = 0; i < 8; ++i)
        #pragma unroll
        for (int j = 0; j < 8; ++j) acc[i][j] = 0.f;

    for (int kt = 0; kt < K; kt += BK) {
        // A tile: 128x16, 8 elems/thread.  k = tid%16, m walks 16..127
        {
            const int k  = tid % 16;
            const int m0 = tid / 16;
            #pragma unroll
            for (int r = 0; r < 8; ++r) {
                const int m  = m0 + r * 16;
                const int gm = bm + m;
                float v = 0.f;
                if (gm < M) v = A[(size_t)gm * lda + (kt + k)];
                As[k][m] = v;
            }
        }
        // B tile: 16x128, 8 elems/thread.  n = tid%128, k walks 2..15
        {
            const int n  = tid % 128;
            const int k0 = tid / 128;
            #pragma unroll
            for (int r = 0; r < 8; ++r) {
                const int k  = k0 + r * 2;
                const int gn = bn + n;
                float v = 0.f;
                if (gn < N) v = B[(size_t)(kt + k) * ldb + gn];
                Bs[k][n] = v;
            }
        }
        __syncthreads();

        #pragma unroll
        for (int kk = 0; kk < BK; ++kk) {
            float a[8], b[8];
            float4 a0 = *(const float4*)&As[kk][ty * 8];
            float4 a1 = *(const float4*)&As[kk][ty * 8 + 4];
            float4 b0 = *(const float4*)&Bs[kk][tx * 8];
            float4 b1 = *(const float4*)&Bs[kk][tx * 8 + 4];
            a[0]=a0.x; a[1]=a0.y; a[2]=a0.z; a[3]=a0.w;
            a[4]=a1.x; a[5]=a1.y; a[6]=a1.z; a[7]=a1.w;
            b[0]=b0.x; b[1]=b0.y; b[2]=b0.z; b[3]=b0.w;
            b[4]=b1.x; b[5]=b1.y; b[6]=b1.z; b[7]=b1.w;
            #pragma unroll
            for (int i = 0; i < 8; ++i)
                #pragma unroll
                for (int j = 0; j < 8; ++j)
                    acc[i][j] = fmaf(a[i], b[j], acc[i][j]);
        }
        __syncthreads();
    }

    #pragma unroll
    for (int i = 0; i < 8; ++i) {
        const int gm = bm + ty * 8 + i;
        if (gm >= M) continue;
        #pragma unroll
        for (int j = 0; j < 8; ++j) {
            const int gn = bn + tx * 8 + j;
            if (gn >= N) continue;
            float v = acc[i][j];
            if (EPI == 1) {
                v += bias[gn];
                v = (v > 20.f) ? v : log1pf(__expf(v));   // softplus
            }
            C[(size_t)gm * ldc + gn] = v;
        }
    }
}

// ---------------------------------------------------------------------------
// Depthwise causal conv (width 4) + bias + SiLU.  in = x half of xz.
// ---------------------------------------------------------------------------
__global__ __launch_bounds__(256) void conv_silu_kernel(
    const float* __restrict__ xz, const float* __restrict__ w,
    const float* __restrict__ cb, float* __restrict__ u)
{
    const int idx = blockIdx.x * 256 + threadIdx.x;   // over NROWS*D_INNER
    if (idx >= NROWS * D_INNER) return;
    const int d   = idx % D_INNER;
    const int row = idx / D_INNER;                    // b*SEQLEN + l
    const int l   = row % SEQLEN;
    float acc = cb[d];
    #pragma unroll
    for (int k = 0; k < D_CONVW; ++k) {
        const int ll = l - 3 + k;
        if (ll >= 0)
            acc = fmaf(xz[(size_t)(row - 3 + k) * (2 * D_INNER) + d], w[d * 4 + k], acc);
    }
    u[idx] = acc / (1.f + __expf(-acc));              // silu
}

// ---------------------------------------------------------------------------
// Per-row softmax over B (16) + copy C (16) out of xp.
// ---------------------------------------------------------------------------
__global__ __launch_bounds__(256) void softmax_bc_kernel(
    const float* __restrict__ xp, float* __restrict__ Bsm, float* __restrict__ Csm)
{
    const int row = blockIdx.x * 256 + threadIdx.x;
    if (row >= NROWS) return;
    const float* p = xp + (size_t)row * 1568;
    float v[16];
    #pragma unroll
    for (int q = 0; q < 4; ++q) {
        float4 t = *(const float4*)(p + q * 4);
        v[q*4+0]=t.x; v[q*4+1]=t.y; v[q*4+2]=t.z; v[q*4+3]=t.w;
    }
    float mx = v[0];
    #pragma unroll
    for (int s = 1; s < 16; ++s) mx = fmaxf(mx, v[s]);
    float sum = 0.f;
    #pragma unroll
    for (int s = 0; s < 16; ++s) { v[s] = __expf(v[s] - mx); sum += v[s]; }
    const float inv = 1.f / sum;
    float* bo = Bsm + (size_t)row * 16;
    float* co = Csm + (size_t)row * 16;
    #pragma unroll
    for (int s = 0; s < 16; ++s) bo[s] = v[s] * inv;
    #pragma unroll
    for (int q = 0; q < 4; ++q)
        *(float4*)(co + q * 4) = *(const float4*)(p + 16 + q * 4);
}

// ---------------------------------------------------------------------------
// Scan phase A: per (b, chunk, d) compute chunk-final state (zero init) and
// chunk dt-sum.  h_t = exp(dt*A)*h + dt*B_t*u_t.
// ---------------------------------------------------------------------------
__global__ __launch_bounds__(256) void scan_chunk_state(
    const float* __restrict__ delta, const float* __restrict__ u,
    const float* __restrict__ Bsm, const float* __restrict__ A_log,
    float* __restrict__ chunkS, float* __restrict__ dtsum)
{
    const int gid = blockIdx.x * 256 + threadIdx.x;   // (b*NCHUNK + c)*D_INNER + d
    const int d = gid % D_INNER;
    const int c = (gid / D_INNER) % NCHUNK;
    const int b = gid / (D_INNER * NCHUNK);

    float A2[16];
    #pragma unroll
    for (int q = 0; q < 4; ++q) {
        float4 t = *(const float4*)(A_log + d * 16 + q * 4);
        A2[q*4+0] = -__expf(t.x) * 1.44269504089f;
        A2[q*4+1] = -__expf(t.y) * 1.44269504089f;
        A2[q*4+2] = -__expf(t.z) * 1.44269504089f;
        A2[q*4+3] = -__expf(t.w) * 1.44269504089f;
    }
    float h[16];
    #pragma unroll
    for (int s = 0; s < 16; ++s) h[s] = 0.f;
    float dts = 0.f;

    const int t0 = c * LCHUNK;
    for (int t = t0; t < t0 + LCHUNK; ++t) {
        const size_t rowoff = (size_t)b * SEQLEN + t;
        const float dt = delta[rowoff * D_INNER + d];
        const float uu = u[rowoff * D_INNER + d];
        const float du = dt * uu;
        dts += dt;
        const float4* Bp = (const float4*)(Bsm + rowoff * 16);
        float Bv[16];
        #pragma unroll
        for (int q = 0; q < 4; ++q) {
            float4 tb = Bp[q];
            Bv[q*4+0]=tb.x; Bv[q*4+1]=tb.y; Bv[q*4+2]=tb.z; Bv[q*4+3]=tb.w;
        }
        #pragma unroll
        for (int s = 0; s < 16; ++s) {
            const float dA = exp2f(dt * A2[s]);
            h[s] = fmaf(dA, h[s], du * Bv[s]);
        }
    }
    float* S = chunkS + (size_t)gid * 16;
    #pragma unroll
    for (int q = 0; q < 4; ++q)
        *(float4*)(S + q * 4) = make_float4(h[q*4+0], h[q*4+1], h[q*4+2], h[q*4+3]);
    dtsum[gid] = dts;
}

// ---------------------------------------------------------------------------
// Scan phase B: inter-chunk scan.  Overwrites chunkS with chunk-INITIAL states.
// One thread per (b,d,s); 32 sequential chunks.
// ---------------------------------------------------------------------------
__global__ __launch_bounds__(256) void scan_chunk_scan(
    const float* __restrict__ A_log, const float* __restrict__ dtsum,
    float* __restrict__ chunkS)
{
    const int gid = blockIdx.x * 256 + threadIdx.x;   // (b*D_INNER + d)*16 + s
    if (gid >= BATCH * D_INNER * 16) return;
    const int s = gid % 16;
    const int d = (gid / 16) % D_INNER;
    const int b = gid / (16 * D_INNER);
    const float A2 = -__expf(A_log[d * 16 + s]) * 1.44269504089f;
    float hprev = 0.f;
    for (int c = 0; c < NCHUNK; ++c) {
        const size_t cidx = ((size_t)(b * NCHUNK + c) * D_INNER + d);
        const float P  = exp2f(A2 * dtsum[cidx]);
        const size_t idx = cidx * 16 + s;
        const float Sc = chunkS[idx];
        chunkS[idx] = hprev;                 // initial state for chunk c
        hprev = fmaf(P, hprev, Sc);
    }
}

// ---------------------------------------------------------------------------
// Scan phase C: re-run chunks from correct initial states, emit
// y[b,t,d] = (sum_s C_s h_s) * silu(z).
// ---------------------------------------------------------------------------
__global__ __launch_bounds__(256) void scan_output(
    const float* __restrict__ delta, const float* __restrict__ u,
    const float* __restrict__ Bsm, const float* __restrict__ Csm,
    const float* __restrict__ A_log, const float* __restrict__ chunkS,
    const float* __restrict__ xz, float* __restrict__ y)
{
    const int gid = blockIdx.x * 256 + threadIdx.x;
    const int d = gid % D_INNER;
    const int c = (gid / D_INNER) % NCHUNK;
    const int b = gid / (D_INNER * NCHUNK);

    float A2[16];
    #pragma unroll
    for (int q = 0; q < 4; ++q) {
        float4 t = *(const float4*)(A_log + d * 16 + q * 4);
        A2[q*4+0] = -__expf(t.x) * 1.44269504089f;
        A2[q*4+1] = -__expf(t.y) * 1.44269504089f;
        A2[q*4+2] = -__expf(t.z) * 1.44269504089f;
        A2[q*4+3] = -__expf(t.w) * 1.44269504089f;
    }
    float h[16];
    const float* S = chunkS + (size_t)gid * 16;
    #pragma unroll
    for (int q = 0; q < 4; ++q) {
        float4 t = *(const float4*)(S + q * 4);
        h[q*4+0]=t.x; h[q*4+1]=t.y; h[q*4+2]=t.z; h[q*4+3]=t.w;
    }

    const int t0 = c * LCHUNK;
    for (int t = t0; t < t0 + LCHUNK; ++t) {
        const size_t rowoff = (size_t)b * SEQLEN + t;
        const float dt = delta[rowoff * D_INNER + d];
        const float uu = u[rowoff * D_INNER + d];
        const float du = dt * uu;
        const float4* Bp = (const float4*)(Bsm + rowoff * 16);
        const float4* Cp = (const float4*)(Csm + rowoff * 16);
        float Bv[16], Cv[16];
        #pragma unroll
        for (int q = 0; q < 4; ++q) {
            float4 tb = Bp[q], tc = Cp[q];
            Bv[q*4+0]=tb.x; Bv[q*4+1]=tb.y; Bv[q*4+2]=tb.z; Bv[q*4+3]=tb.w;
            Cv[q*4+0]=tc.x; Cv[q*4+1]=tc.y; Cv[q*4+2]=tc.z; Cv[q*4+3]=tc.w;
        }
        float yv = 0.f;
        #pragma unroll
        for (int s = 0; s < 16; ++s) {
            const float dA = exp2f(dt * A2[s]);
            h[s] = fmaf(dA, h[s], du * Bv[s]);
            yv = fmaf(Cv[s], h[s], yv);
        }
        const float z = xz[rowoff * (2 * D_INNER) + D_INNER + d];
        const float sz = z / (1.f + __expf(-z));
        y[rowoff * D_INNER + d] = yv * sz;
    }
}

// ---------------------------------------------------------------------------
extern "C" void kernel_launch(void* const* d_in, const int* in_sizes, int n_in,
                              void* d_out, int out_size, void* d_ws, size_t ws_size,
                              hipStream_t stream)
{
    const float* hs     = (const float*)d_in[0];
    const float* W_in   = (const float*)d_in[1];
    const float* conv_w = (const float*)d_in[2];
    const float* conv_b = (const float*)d_in[3];
    const float* W_x    = (const float*)d_in[4];
    const float* W_dt   = (const float*)d_in[5];
    const float* b_dt   = (const float*)d_in[6];
    const float* A_log  = (const float*)d_in[7];
    // d_in[8] = D : unused by the reference computation
    const float* W_out  = (const float*)d_in[9];
    float* out = (float*)d_out;

    float* ws     = (float*)d_ws;
    float* xz     = ws;                                    // 8192*3072
    float* u      = xz  + (size_t)NROWS * 3072;            // 8192*1536
    float* xp     = u   + (size_t)NROWS * 1536;            // 8192*1568
    float* delta  = xp  + (size_t)NROWS * 1568;            // 8192*1536
    float* Bsm    = delta + (size_t)NROWS * 1536;          // 8192*16
    float* Csm    = Bsm + (size_t)NROWS * 16;              // 8192*16
    float* chunkS = Csm + (size_t)NROWS * 16;              // 2*32*1536*16
    float* dtsum  = chunkS + (size_t)BATCH * NCHUNK * D_INNER * 16; // 2*32*1536
    float* y      = xp;  // reuse xp's memory after delta GEMM consumed it

    const dim3 blk(256);

    // 1) xz = hs @ W_in       (8192 x 768 x 3072)
    gemm_f32<0><<<dim3(3072/128, NROWS/128), blk, 0, stream>>>(
        hs, D_MODEL, W_in, 2*D_INNER, xz, 2*D_INNER, NROWS, 2*D_INNER, D_MODEL, nullptr);

    // 2) u = silu(conv(x) + cb)
    conv_silu_kernel<<<(NROWS*D_INNER)/256, blk, 0, stream>>>(xz, conv_w, conv_b, u);

    // 3) xp = u @ W_x          (8192 x 1536 x 1568)
    gemm_f32<0><<<dim3((1568+127)/128, NROWS/128), blk, 0, stream>>>(
        u, D_INNER, W_x, 1568, xp, 1568, NROWS, 1568, D_INNER, nullptr);

    // 4) Bsm = softmax(xp[:, :16]), Csm = xp[:, 16:32]
    softmax_bc_kernel<<<NROWS/256, blk, 0, stream>>>(xp, Bsm, Csm);

    // 5) delta = softplus(xp[:, 32:] @ W_dt + b_dt)   (8192 x 1536 x 1536)
    gemm_f32<1><<<dim3(1536/128, NROWS/128), blk, 0, stream>>>(
        xp + 32, 1568, W_dt, D_INNER, delta, D_INNER, NROWS, D_INNER, D_INNER, b_dt);

    // 6-8) chunked selective scan
    scan_chunk_state<<<(BATCH*NCHUNK*D_INNER)/256, blk, 0, stream>>>(
        delta, u, Bsm, A_log, chunkS, dtsum);
    scan_chunk_scan<<<(BATCH*D_INNER*16)/256, blk, 0, stream>>>(
        A_log, dtsum, chunkS);
    scan_output<<<(BATCH*NCHUNK*D_INNER)/256, blk, 0, stream>>>(
        delta, u, Bsm, Csm, A_log, chunkS, xz, y);

    // 9) out = y @ W_out       (8192 x 1536 x 768)
    gemm_f32<0><<<dim3(768/128, NROWS/128), blk, 0, stream>>>(
        y, D_INNER, W_out, D_MODEL, out, D_MODEL, NROWS, D_MODEL, D_INNER, nullptr);
}

// Round 2
// 681.540 us; speedup vs baseline: 5.0009x; 5.0009x over previous
//
#include <hip/hip_runtime.h>
#include <hip/hip_bf16.h>
#include <math.h>

#define D_MODEL 768
#define D_STATE 16
#define D_CONVW 4
#define D_INNER 1536
#define BATCH   2
#define SEQLEN  4096
#define NROWS   (BATCH*SEQLEN)       // 8192
#define NCHUNK  32
#define LCHUNK  (SEQLEN/NCHUNK)      // 128

typedef __attribute__((ext_vector_type(8))) short short8;
typedef __attribute__((ext_vector_type(4))) float floatx4;

__device__ inline unsigned short f2b(float x) {
    unsigned u = __float_as_uint(x);
    return (unsigned short)((u + 0x7fffu + ((u >> 16) & 1u)) >> 16);   // RNE
}
__device__ inline float b2f(unsigned short b) {
    return __uint_as_float(((unsigned)b) << 16);
}

// ---------------------------------------------------------------------------
// bf16 MFMA GEMM (m97 structure): C[M,N] = A[M,K] @ B[K,N], B given as
// Bt[N_pad][K] bf16 row-major.  128x128 tile, BK=32, 256 thr = 4 waves,
// each wave a 64x64 quadrant via 4x4 mfma_f32_16x16x32_bf16 fragments.
// EPI: 0 none, 1 softplus(acc+bias[n]).  OUTBF16: write bf16 instead of f32.
// ---------------------------------------------------------------------------
template<int EPI, int OUTBF16>
__global__ __launch_bounds__(256) void gemm_bf16(
    const unsigned short* __restrict__ A, int lda,
    const unsigned short* __restrict__ Bt, int ldb,
    void* __restrict__ Cv, int ldc, int N, int K,
    const float* __restrict__ bias)
{
    __shared__ unsigned short As[128 * 32];
    __shared__ unsigned short Bs[128 * 32];
    const int tid  = threadIdx.x;
    const int lane = tid & 63;
    const int wave = tid >> 6;
    const int wm   = (wave >> 1) * 64;
    const int wn   = (wave & 1) * 64;
    const int bm   = blockIdx.y * 128;
    const int bn   = blockIdx.x * 128;
    const int l15  = lane & 15;
    const int lg   = lane >> 4;            // 0..3 (k-group)

    // staging decomposition: elem e = (p*256+tid)*8 -> row=e/32, col=e%32
    const int sr = tid >> 2;               // + p*64
    const int sc = (tid & 3) * 8;
    const int lbase = (tid & ~63) * 16;    // + p*4096 bytes

    floatx4 acc[4][4] = {};

    for (int kt = 0; kt < K; kt += 32) {
        #pragma unroll
        for (int p = 0; p < 2; ++p) {
            const unsigned short* ga = A + (size_t)(bm + p * 64 + sr) * lda + kt + sc;
            char* la = (char*)As + p * 4096 + lbase;
            __builtin_amdgcn_global_load_lds(
                (const __attribute__((address_space(1))) void*)ga,
                (__attribute__((address_space(3))) void*)la, 16, 0, 0);
            const unsigned short* gb = Bt + (size_t)(bn + p * 64 + sr) * ldb + kt + sc;
            char* lb = (char*)Bs + p * 4096 + lbase;
            __builtin_amdgcn_global_load_lds(
                (const __attribute__((address_space(1))) void*)gb,
                (__attribute__((address_space(3))) void*)lb, 16, 0, 0);
        }
        __syncthreads();

        short8 af[4], bfr[4];
        #pragma unroll
        for (int i = 0; i < 4; ++i)
            af[i] = *(const short8*)&As[(wm + i * 16 + l15) * 32 + lg * 8];
        #pragma unroll
        for (int j = 0; j < 4; ++j)
            bfr[j] = *(const short8*)&Bs[(wn + j * 16 + l15) * 32 + lg * 8];
        #pragma unroll
        for (int i = 0; i < 4; ++i)
            #pragma unroll
            for (int j = 0; j < 4; ++j)
                acc[i][j] = __builtin_amdgcn_mfma_f32_16x16x32_bf16(
                    af[i], bfr[j], acc[i][j], 0, 0, 0);
        __syncthreads();
    }

    // C/D layout (m89-verified): col = lane&15, row = (lane>>4)*4 + reg
    #pragma unroll
    for (int i = 0; i < 4; ++i) {
        #pragma unroll
        for (int r = 0; r < 4; ++r) {
            const int gm = bm + wm + i * 16 + lg * 4 + r;
            #pragma unroll
            for (int j = 0; j < 4; ++j) {
                const int gn = bn + wn + j * 16 + l15;
                if (gn < N) {
                    float v = acc[i][j][r];
                    if (EPI == 1) {
                        v += bias[gn];
                        v = (v > 20.f) ? v : log1pf(__expf(v));   // softplus
                    }
                    if (OUTBF16)
                        ((unsigned short*)Cv)[(size_t)gm * ldc + gn] = f2b(v);
                    else
                        ((float*)Cv)[(size_t)gm * ldc + gn] = v;
                }
            }
        }
    }
}

// ---------------------------------------------------------------------------
// W[K][N] f32 -> Wt[N_pad][K] bf16 (pad rows zeroed).  32x32 LDS transpose.
// grid = (Npad/32, K/32), block 256.
// ---------------------------------------------------------------------------
__global__ __launch_bounds__(256) void transpose_bf16(
    const float* __restrict__ W, unsigned short* __restrict__ Wt, int K, int N)
{
    __shared__ float t[32][33];
    const int nt = blockIdx.x * 32, kt = blockIdx.y * 32;
    const int tx = threadIdx.x & 31, ty = threadIdx.x >> 5;
    #pragma unroll
    for (int r = 0; r < 4; ++r) {
        const int k = ty + r * 8;
        const int n = nt + tx;
        float v = 0.f;
        if (n < N) v = W[(size_t)(kt + k) * N + n];
        t[k][tx] = v;
    }
    __syncthreads();
    #pragma unroll
    for (int r = 0; r < 4; ++r) {
        const int nl = ty + r * 8;
        Wt[(size_t)(nt + nl) * K + kt + tx] = f2b(t[tx][nl]);
    }
}

// flat f32 -> bf16, 4 elems/thread
__global__ __launch_bounds__(256) void f32_to_bf16(
    const float* __restrict__ in, unsigned short* __restrict__ o, int n4)
{
    const int i = blockIdx.x * 256 + threadIdx.x;
    if (i >= n4) return;
    float4 v = ((const float4*)in)[i];
    ushort4 r;
    r.x = f2b(v.x); r.y = f2b(v.y); r.z = f2b(v.z); r.w = f2b(v.w);
    ((ushort4*)o)[i] = r;
}

// xp[:, 32:1568] f32 -> xpdtb[8192][1536] bf16
__global__ __launch_bounds__(256) void xp_to_bf16(
    const float* __restrict__ xp, unsigned short* __restrict__ o)
{
    const int i = blockIdx.x * 256 + threadIdx.x;   // over 8192*384
    if (i >= NROWS * 384) return;
    const int row = i / 384, q = i % 384;
    float4 v = *(const float4*)(xp + (size_t)row * 1568 + 32 + q * 4);
    ushort4 r;
    r.x = f2b(v.x); r.y = f2b(v.y); r.z = f2b(v.z); r.w = f2b(v.w);
    *(ushort4*)(o + (size_t)row * 1536 + q * 4) = r;
}

// ---------------------------------------------------------------------------
// Depthwise causal conv (width 4) + bias + SiLU, bf16 in/out (f32 math).
// ---------------------------------------------------------------------------
__global__ __launch_bounds__(256) void conv_silu_kernel(
    const unsigned short* __restrict__ xzb, const float* __restrict__ w,
    const float* __restrict__ cb, unsigned short* __restrict__ ub)
{
    const int idx = blockIdx.x * 256 + threadIdx.x;
    if (idx >= NROWS * D_INNER) return;
    const int d   = idx % D_INNER;
    const int row = idx / D_INNER;
    const int l   = row % SEQLEN;
    float acc = cb[d];
    #pragma unroll
    for (int k = 0; k < D_CONVW; ++k) {
        const int ll = l - 3 + k;
        if (ll >= 0)
            acc = fmaf(b2f(xzb[(size_t)(row - 3 + k) * (2 * D_INNER) + d]),
                       w[d * 4 + k], acc);
    }
    ub[idx] = f2b(acc / (1.f + __expf(-acc)));
}

// ---------------------------------------------------------------------------
// Per-row softmax over B (16) + copy C (16) out of xp (f32).
// ---------------------------------------------------------------------------
__global__ __launch_bounds__(256) void softmax_bc_kernel(
    const float* __restrict__ xp, float* __restrict__ Bsm, float* __restrict__ Csm)
{
    const int row = blockIdx.x * 256 + threadIdx.x;
    if (row >= NROWS) return;
    const float* p = xp + (size_t)row * 1568;
    float v[16];
    #pragma unroll
    for (int q = 0; q < 4; ++q) {
        float4 t = *(const float4*)(p + q * 4);
        v[q*4+0]=t.x; v[q*4+1]=t.y; v[q*4+2]=t.z; v[q*4+3]=t.w;
    }
    float mx = v[0];
    #pragma unroll
    for (int s = 1; s < 16; ++s) mx = fmaxf(mx, v[s]);
    float sum = 0.f;
    #pragma unroll
    for (int s = 0; s < 16; ++s) { v[s] = __expf(v[s] - mx); sum += v[s]; }
    const float inv = 1.f / sum;
    float* bo = Bsm + (size_t)row * 16;
    float* co = Csm + (size_t)row * 16;
    #pragma unroll
    for (int s = 0; s < 16; ++s) bo[s] = v[s] * inv;
    #pragma unroll
    for (int q = 0; q < 4; ++q)
        *(float4*)(co + q * 4) = *(const float4*)(p + 16 + q * 4);
}

// ---------------------------------------------------------------------------
// Scan phase A: per (b, chunk, d): chunk-final state (zero init) + dt-sum.
// ---------------------------------------------------------------------------
__global__ __launch_bounds__(256) void scan_chunk_state(
    const float* __restrict__ delta, const unsigned short* __restrict__ ub,
    const float* __restrict__ Bsm, const float* __restrict__ A_log,
    float* __restrict__ chunkS, float* __restrict__ dtsum)
{
    const int gid = blockIdx.x * 256 + threadIdx.x;   // (b*NCHUNK+c)*D_INNER+d
    const int d = gid % D_INNER;
    const int c = (gid / D_INNER) % NCHUNK;
    const int b = gid / (D_INNER * NCHUNK);

    float A2[16];
    #pragma unroll
    for (int q = 0; q < 4; ++q) {
        float4 t = *(const float4*)(A_log + d * 16 + q * 4);
        A2[q*4+0] = -__expf(t.x) * 1.44269504089f;
        A2[q*4+1] = -__expf(t.y) * 1.44269504089f;
        A2[q*4+2] = -__expf(t.z) * 1.44269504089f;
        A2[q*4+3] = -__expf(t.w) * 1.44269504089f;
    }
    float h[16];
    #pragma unroll
    for (int s = 0; s < 16; ++s) h[s] = 0.f;
    float dts = 0.f;

    const int t0 = c * LCHUNK;
    for (int t = t0; t < t0 + LCHUNK; ++t) {
        const size_t rowoff = (size_t)b * SEQLEN + t;
        const float dt = delta[rowoff * D_INNER + d];
        const float uu = b2f(ub[rowoff * D_INNER + d]);
        const float du = dt * uu;
        dts += dt;
        const float4* Bp = (const float4*)(Bsm + rowoff * 16);
        float Bv[16];
        #pragma unroll
        for (int q = 0; q < 4; ++q) {
            float4 tb = Bp[q];
            Bv[q*4+0]=tb.x; Bv[q*4+1]=tb.y; Bv[q*4+2]=tb.z; Bv[q*4+3]=tb.w;
        }
        #pragma unroll
        for (int s = 0; s < 16; ++s) {
            const float dA = exp2f(dt * A2[s]);
            h[s] = fmaf(dA, h[s], du * Bv[s]);
        }
    }
    float* S = chunkS + (size_t)gid * 16;
    #pragma unroll
    for (int q = 0; q < 4; ++q)
        *(float4*)(S + q * 4) = make_float4(h[q*4+0], h[q*4+1], h[q*4+2], h[q*4+3]);
    dtsum[gid] = dts;
}

// ---------------------------------------------------------------------------
// Scan phase B: inter-chunk scan; chunkS becomes chunk-INITIAL states.
// ---------------------------------------------------------------------------
__global__ __launch_bounds__(256) void scan_chunk_scan(
    const float* __restrict__ A_log, const float* __restrict__ dtsum,
    float* __restrict__ chunkS)
{
    const int gid = blockIdx.x * 256 + threadIdx.x;   // (b*D_INNER+d)*16+s
    if (gid >= BATCH * D_INNER * 16) return;
    const int s = gid % 16;
    const int d = (gid / 16) % D_INNER;
    const int b = gid / (16 * D_INNER);
    const float A2 = -__expf(A_log[d * 16 + s]) * 1.44269504089f;
    float hprev = 0.f;
    for (int c = 0; c < NCHUNK; ++c) {
        const size_t cidx = ((size_t)(b * NCHUNK + c) * D_INNER + d);
        const float P  = exp2f(A2 * dtsum[cidx]);
        const size_t idx = cidx * 16 + s;
        const float Sc = chunkS[idx];
        chunkS[idx] = hprev;
        hprev = fmaf(P, hprev, Sc);
    }
}

// ---------------------------------------------------------------------------
// Scan phase C: re-run chunks from initial states, y = (C.h) * silu(z), bf16.
// ---------------------------------------------------------------------------
__global__ __launch_bounds__(256) void scan_output(
    const float* __restrict__ delta, const unsigned short* __restrict__ ub,
    const float* __restrict__ Bsm, const float* __restrict__ Csm,
    const float* __restrict__ A_log, const float* __restrict__ chunkS,
    const unsigned short* __restrict__ xzb, unsigned short* __restrict__ yb)
{
    const int gid = blockIdx.x * 256 + threadIdx.x;
    const int d = gid % D_INNER;
    const int c = (gid / D_INNER) % NCHUNK;
    const int b = gid / (D_INNER * NCHUNK);

    float A2[16];
    #pragma unroll
    for (int q = 0; q < 4; ++q) {
        float4 t = *(const float4*)(A_log + d * 16 + q * 4);
        A2[q*4+0] = -__expf(t.x) * 1.44269504089f;
        A2[q*4+1] = -__expf(t.y) * 1.44269504089f;
        A2[q*4+2] = -__expf(t.z) * 1.44269504089f;
        A2[q*4+3] = -__expf(t.w) * 1.44269504089f;
    }
    float h[16];
    const float* S = chunkS + (size_t)gid * 16;
    #pragma unroll
    for (int q = 0; q < 4; ++q) {
        float4 t = *(const float4*)(S + q * 4);
        h[q*4+0]=t.x; h[q*4+1]=t.y; h[q*4+2]=t.z; h[q*4+3]=t.w;
    }

    const int t0 = c * LCHUNK;
    for (int t = t0; t < t0 + LCHUNK; ++t) {
        const size_t rowoff = (size_t)b * SEQLEN + t;
        const float dt = delta[rowoff * D_INNER + d];
        const float uu = b2f(ub[rowoff * D_INNER + d]);
        const float du = dt * uu;
        const float4* Bp = (const float4*)(Bsm + rowoff * 16);
        const float4* Cp = (const float4*)(Csm + rowoff * 16);
        float Bv[16], Cv[16];
        #pragma unroll
        for (int q = 0; q < 4; ++q) {
            float4 tb = Bp[q], tc = Cp[q];
            Bv[q*4+0]=tb.x; Bv[q*4+1]=tb.y; Bv[q*4+2]=tb.z; Bv[q*4+3]=tb.w;
            Cv[q*4+0]=tc.x; Cv[q*4+1]=tc.y; Cv[q*4+2]=tc.z; Cv[q*4+3]=tc.w;
        }
        float yv = 0.f;
        #pragma unroll
        for (int s = 0; s < 16; ++s) {
            const float dA = exp2f(dt * A2[s]);
            h[s] = fmaf(dA, h[s], du * Bv[s]);
            yv = fmaf(Cv[s], h[s], yv);
        }
        const float z = b2f(xzb[rowoff * (2 * D_INNER) + D_INNER + d]);
        const float sz = z / (1.f + __expf(-z));
        yb[rowoff * D_INNER + d] = f2b(yv * sz);
    }
}

// ---------------------------------------------------------------------------
extern "C" void kernel_launch(void* const* d_in, const int* in_sizes, int n_in,
                              void* d_out, int out_size, void* d_ws, size_t ws_size,
                              hipStream_t stream)
{
    const float* hs     = (const float*)d_in[0];
    const float* W_in   = (const float*)d_in[1];
    const float* conv_w = (const float*)d_in[2];
    const float* conv_b = (const float*)d_in[3];
    const float* W_x    = (const float*)d_in[4];
    const float* W_dt   = (const float*)d_in[5];
    const float* b_dt   = (const float*)d_in[6];
    const float* A_log  = (const float*)d_in[7];
    const float* W_out  = (const float*)d_in[9];
    float* out = (float*)d_out;

    // workspace layout (all offsets 256B aligned), total ~240 MB
    char* w = (char*)d_ws;
    auto alloc = [&](size_t bytes) { char* p = w; w += (bytes + 255) & ~(size_t)255; return p; };
    float*          xp     = (float*)alloc((size_t)NROWS * 1568 * 4);
    float*          delta  = (float*)alloc((size_t)NROWS * 1536 * 4);
    float*          Bsm    = (float*)alloc((size_t)NROWS * 16 * 4);
    float*          Csm    = (float*)alloc((size_t)NROWS * 16 * 4);
    float*          chunkS = (float*)alloc((size_t)BATCH * NCHUNK * D_INNER * 16 * 4);
    float*          dtsum  = (float*)alloc((size_t)BATCH * NCHUNK * D_INNER * 4);
    unsigned short* xzb    = (unsigned short*)alloc((size_t)NROWS * 3072 * 2);
    unsigned short* ub     = (unsigned short*)alloc((size_t)NROWS * 1536 * 2);
    unsigned short* xpdtb  = (unsigned short*)alloc((size_t)NROWS * 1536 * 2);
    unsigned short* hsb    = (unsigned short*)alloc((size_t)NROWS * 768 * 2);
    unsigned short* Wt_in  = (unsigned short*)alloc((size_t)3072 * 768 * 2);
    unsigned short* Wt_x   = (unsigned short*)alloc((size_t)1664 * 1536 * 2);
    unsigned short* Wt_dt  = (unsigned short*)alloc((size_t)1536 * 1536 * 2);
    unsigned short* Wt_out = (unsigned short*)alloc((size_t)768 * 1536 * 2);
    unsigned short* yb     = (unsigned short*)xp;   // xp dead before scan_output

    const dim3 blk(256);

    // 0) weight transposes + input convert
    transpose_bf16<<<dim3(3072/32, 768/32),  blk, 0, stream>>>(W_in,  Wt_in,  768,  3072);
    transpose_bf16<<<dim3(1664/32, 1536/32), blk, 0, stream>>>(W_x,   Wt_x,   1536, 1568);
    transpose_bf16<<<dim3(1536/32, 1536/32), blk, 0, stream>>>(W_dt,  Wt_dt,  1536, 1536);
    transpose_bf16<<<dim3(768/32,  1536/32), blk, 0, stream>>>(W_out, Wt_out, 1536, 768);
    f32_to_bf16<<<(NROWS*768/4 + 255)/256, blk, 0, stream>>>(hs, hsb, NROWS*768/4);

    // 1) xz = hs @ W_in  (bf16 out)
    gemm_bf16<0,1><<<dim3(3072/128, NROWS/128), blk, 0, stream>>>(
        hsb, 768, Wt_in, 768, xzb, 3072, 3072, 768, nullptr);

    // 2) u = silu(conv(x) + cb)  (bf16)
    conv_silu_kernel<<<(NROWS*D_INNER)/256, blk, 0, stream>>>(xzb, conv_w, conv_b, ub);

    // 3) xp = u @ W_x  (f32 out, N=1568 with pad-guard)
    gemm_bf16<0,0><<<dim3(1664/128, NROWS/128), blk, 0, stream>>>(
        ub, 1536, Wt_x, 1536, xp, 1568, 1568, 1536, nullptr);

    // 4) Bsm = softmax(xp[:, :16]), Csm = xp[:, 16:32]
    softmax_bc_kernel<<<NROWS/256, blk, 0, stream>>>(xp, Bsm, Csm);

    // 5) xp[:, 32:] -> bf16; delta = softplus(xpdt @ W_dt + b_dt)
    xp_to_bf16<<<(NROWS*384)/256, blk, 0, stream>>>(xp, xpdtb);
    gemm_bf16<1,0><<<dim3(1536/128, NROWS/128), blk, 0, stream>>>(
        xpdtb, 1536, Wt_dt, 1536, delta, 1536, 1536, 1536, b_dt);

    // 6-8) chunked selective scan (yb aliases xp — xp fully consumed above)
    scan_chunk_state<<<(BATCH*NCHUNK*D_INNER)/256, blk, 0, stream>>>(
        delta, ub, Bsm, A_log, chunkS, dtsum);
    scan_chunk_scan<<<(BATCH*D_INNER*16 + 255)/256, blk, 0, stream>>>(
        A_log, dtsum, chunkS);
    scan_output<<<(BATCH*NCHUNK*D_INNER)/256, blk, 0, stream>>>(
        delta, ub, Bsm, Csm, A_log, chunkS, xzb, yb);

    // 9) out = y @ W_out  (f32 out)
    gemm_bf16<0,0><<<dim3(768/128, NROWS/128), blk, 0, stream>>>(
        yb, 1536, Wt_out, 1536, out, 768, 768, 1536, nullptr);
}